// Round 1
// 105.289 us; speedup vs baseline: 1.0039x; 1.0039x over previous
//
#include <hip/hip_runtime.h>

#define BB 32
#define NP 2048
#define NG 2048
#define EPSF 1e-6f
#define BIGF 1e18f
#define FLTMAX 3.4e38f
#define MT 128   // m-tile staged in LDS per block
#define MP 16    // partials per side
#define TPT 4    // points per thread: ~40 live VGPRs -> fits 64-VGPR/8-wave occupancy

// ws layout (all regions fully overwritten every call -> no init memsets):
//  [0, 8448)            : fpart[264][8] floats (k_fin per-block partial sums)
//  [8448, 8452)         : u32 completion counter (zeroed by k_pair each call;
//                         poison value is unknown so we cannot rely on it)
//  [65536, +8MB)        : pred partials u64 [b][mp][n]  (dist_bits<<32 | idx)
//  [65536+8MB, +4MB)    : tgt partials f32 [b][np][m]
#define FPART_OFF 0
#define CNT_OFF 8448
#define PPART_OFF 65536
#define TPART_OFF (65536 + BB * MP * NP * 8)

// Agent-scope coherent load: bypasses the (possibly stale, non-coherent)
// per-XCD caches when the last k_fin block reads rows produced on other XCDs.
__device__ __forceinline__ float cload(const float* p) {
  return __hip_atomic_load(p, __ATOMIC_RELAXED, __HIP_MEMORY_SCOPE_AGENT);
}

// Fused pairwise kernel. Blocks [0,1024): pred side (masked min+argmin over
// targets); blocks [1024,2048): tgt side (unmasked min over preds).
// Per side: 32 b * 2 nch * 16 mp. Each thread owns 4 points (stride 256),
// 128 opposite-side points staged in LDS (broadcast b128 reads).
// launch_bounds(256,8) caps VGPR at 64 -> 8 waves/SIMD, 32 waves/CU with
// 8 blocks/CU: latency-hiding was the R5 bottleneck (4 waves/SIMD).
// This kernel is at its VALU issue floor (~17 us); structure frozen.
__global__ __launch_bounds__(256, 8) void k_pair(const float* __restrict__ preds,
                                                 const float* __restrict__ target,
                                                 const float* __restrict__ mask,
                                                 unsigned long long* __restrict__ ppart,
                                                 float* __restrict__ tpart,
                                                 unsigned* __restrict__ cnt) {
  __shared__ float4 s4[MT];
  const int bx = blockIdx.x;
  const int tid = threadIdx.x;

  if (bx == 0 && tid == 0) *cnt = 0;  // reset for k_fin's last-block detect;
                                      // kernel-boundary release makes it visible

  if (bx < 1024) {
    // ---- pred side ----
    const int b = bx >> 5;
    const int nch = (bx >> 4) & 1;
    const int mp = bx & 15;
    const float* tb = target + b * 4 * NG;
    const int mbase = mp * MT;
    if (tid < MT) {
      int m = mbase + tid;
      float tx = tb[m], ty = tb[NG + m], tz = tb[2 * NG + m];
      float tn = fmaf(tx, tx, fmaf(ty, ty, tz * tz));
      float w = tn + (mask[b * NG + m] == 0.0f ? BIGF : 0.0f);  // fold BIG mask
      s4[tid] = make_float4(-2.0f * tx, -2.0f * ty, -2.0f * tz, w);
    }
    __syncthreads();

    const float* pb = preds + b * 5 * NP;
    const int nbase = nch * 1024 + tid;
    float px[TPT], py[TPT], pz[TPT], bv[TPT];
    int bi[TPT];
#pragma unroll
    for (int k = 0; k < TPT; k++) {
      int n = nbase + k * 256;
      px[k] = pb[n];
      py[k] = pb[NP + n];
      pz[k] = pb[2 * NP + n];
      bv[k] = FLTMAX;
      bi[k] = 0;
    }

    // s = tn - 2*dot (+BIG if masked); pn^2 thread-invariant -> folded out.
    // argmin needed -> cmp+2 cndmask per pair; no min3 possible here.
#pragma unroll 4
    for (int m = 0; m < MT; m++) {
      float4 t = s4[m];
#pragma unroll
      for (int k = 0; k < TPT; k++) {
        float s = fmaf(px[k], t.x, fmaf(py[k], t.y, fmaf(pz[k], t.z, t.w)));
        if (s < bv[k]) { bv[k] = s; bi[k] = m; }  // strict < keeps first index
      }
    }

    unsigned long long* row = &ppart[(b * MP + mp) * NP];
#pragma unroll
    for (int k = 0; k < TPT; k++) {
      float pn = fmaf(px[k], px[k], fmaf(py[k], py[k], pz[k] * pz[k]));
      float d = fmaxf(bv[k] + pn, 0.0f);
      row[nbase + k * 256] =
          ((unsigned long long)__float_as_uint(d) << 32) | (unsigned)(mbase + bi[k]);
    }
  } else {
    // ---- tgt side ----
    const int bb = bx - 1024;
    const int b = bb >> 5;
    const int mch = (bb >> 4) & 1;
    const int np_ = bb & 15;
    const float* pb = preds + b * 5 * NP;
    if (tid < MT) {
      int n = np_ * MT + tid;
      float px = pb[n], py = pb[NP + n], pz = pb[2 * NP + n];
      float pn2 = fmaf(px, px, fmaf(py, py, pz * pz));
      s4[tid] = make_float4(-2.0f * px, -2.0f * py, -2.0f * pz, pn2);
    }
    __syncthreads();

    const float* tb = target + b * 4 * NG;
    const int mbase2 = mch * 1024 + tid;
    float tx[TPT], ty[TPT], tz[TPT], cv[TPT];
#pragma unroll
    for (int k = 0; k < TPT; k++) {
      int m = mbase2 + k * 256;
      tx[k] = tb[m];
      ty[k] = tb[NG + m];
      tz[k] = tb[2 * NG + m];
      cv[k] = FLTMAX;
    }

    // No index needed -> process m in pairs, fminf(fminf(..)) fuses to
    // v_min3_f32: 7 VALU per 2 pairs instead of 8. min is exactly
    // associative for finite inputs -> bit-identical result.
#pragma unroll 2
    for (int n = 0; n < MT; n += 2) {
      float4 p0 = s4[n];
      float4 p1 = s4[n + 1];
#pragma unroll
      for (int k = 0; k < TPT; k++) {
        float s0 = fmaf(tx[k], p0.x, fmaf(ty[k], p0.y, fmaf(tz[k], p0.z, p0.w)));
        float s1 = fmaf(tx[k], p1.x, fmaf(ty[k], p1.y, fmaf(tz[k], p1.z, p1.w)));
        cv[k] = fminf(cv[k], fminf(s0, s1));
      }
    }

    float* row = &tpart[(b * MP + np_) * NG];
#pragma unroll
    for (int k = 0; k < TPT; k++) {
      float tn = fmaf(tx[k], tx[k], fmaf(ty[k], ty[k], tz[k] * tz[k]));
      row[mbase2 + k * 256] = fmaxf(cv[k] + tn, 0.0f);
    }
  }
}

// Combine: blocks [0,128) pred side, [128,256) tgt side, [256,264) kld.
// Reduces 16 partials per point, computes elementwise pieces, block-level
// LDS reduction, writes 5 partial sums to a private slot (no atomics).
// The LAST block to finish (device-scope counter) then performs the final
// loss assembly that used to be a separate 1-block k_final launch -- saves
// one launch + single-block kernel latency. Deterministic: assembly sum
// order is fixed by code, only which block runs it varies.
__global__ __launch_bounds__(256) void k_fin(const unsigned long long* __restrict__ ppart,
                                             const float* __restrict__ tpart,
                                             const float* __restrict__ preds,
                                             const float* __restrict__ target,
                                             const float* __restrict__ mask,
                                             const float* __restrict__ mu,
                                             const float* __restrict__ logvar,
                                             const float* __restrict__ e_init,
                                             const float* __restrict__ kl_weight,
                                             float* __restrict__ fpart,
                                             unsigned* __restrict__ cnt,
                                             float* __restrict__ out) {
  __shared__ float red[4][8];
  __shared__ int s_last;
  const int bx = blockIdx.x;
  const int tid = threadIdx.x;
  const int wave = tid >> 6, lane = tid & 63;
  float q0 = 0.0f, q1 = 0.0f, q2 = 0.0f, q3 = 0.0f, q4 = 0.0f;

  if (bx < 128) {
    const int b = bx >> 2;
    const float* pb = preds + b * 5 * NP;
    const float* te = target + b * 4 * NG + 3 * NG;
#pragma unroll
    for (int e = 0; e < 2; e++) {
      int i = bx * 512 + e * 256 + tid;
      int n = i & 2047;
      unsigned long long best = 0xFFFFFFFFFFFFFFFFull;
      const unsigned long long* col = &ppart[b * MP * NP + n];
#pragma unroll
      for (int mp = 0; mp < MP; mp++) {
        unsigned long long v = col[mp * NP];  // coalesced across lanes
        best = v < best ? v : best;           // min packed: dist then index
      }
      float bd = __uint_as_float((unsigned)(best >> 32));
      int idx = (int)(best & 0xffffffffu);
      float mE = te[idx];
      float pE = pb[3 * NP + n];
      float ph = pb[4 * NP + n];
      q0 += bd;
      q1 += fabsf(pE - mE);
      q2 += ph * logf(ph + EPSF) + (1.0f - ph) * logf(1.0f - ph + EPSF);
      q3 += ph;
      q4 += pE * ph;
    }
  } else if (bx < 256) {
    const int bb = bx - 128;
    const int b = bb >> 2;
#pragma unroll
    for (int e = 0; e < 2; e++) {
      int i = bb * 512 + e * 256 + tid;
      int m = i & 2047;
      float d = FLTMAX;
      const float* col = &tpart[b * MP * NG + m];
#pragma unroll
      for (int np_ = 0; np_ < MP; np_++) d = fminf(d, col[np_ * NG]);
      float msk = mask[i];
      q0 += d * msk;  // sum min_dist_tgt * mask
      q1 += msk;      // global mask sum
      q2 += msk;      // per-b mask sum (same value, separate slot)
    }
  } else {
    const int bb = bx - 256;  // B*L = 8192 over 8 blocks
#pragma unroll
    for (int e = 0; e < 4; e++) {
      int i = bb * 1024 + e * 256 + tid;
      float m = mu[i], lv = logvar[i];
      q0 += 1.0f + lv - m * m - expf(lv);
    }
  }

  float qs[5] = {q0, q1, q2, q3, q4};
  for (int k = 0; k < 5; k++) {
    float v = qs[k];
    v += __shfl_down(v, 32);
    v += __shfl_down(v, 16);
    v += __shfl_down(v, 8);
    v += __shfl_down(v, 4);
    v += __shfl_down(v, 2);
    v += __shfl_down(v, 1);
    if (lane == 0) red[wave][k] = v;
  }
  __syncthreads();
  if (tid < 5) fpart[bx * 8 + tid] = red[0][tid] + red[1][tid] + red[2][tid] + red[3][tid];

  // ---- last-block-done gate ----
  __syncthreads();  // fpart row fully written by tid<5 before the fence
  if (tid == 0) {
    __threadfence();  // agent-scope release of this block's fpart row
    s_last = (atomicAdd(cnt, 1u) == 263u) ? 1 : 0;  // device-scope by default
  }
  __syncthreads();
  if (!s_last) return;

  // ---- final assembly (ex-k_final), in the last-arriving block ----
  // g0 sum_min_pred, g1 sum|dE|, g2 entropy, g3 sum d*msk, g4 mask_sum,
  // g5 kld_sum, g6 hit_sq_sum, g7 esq_sum
  float g[8] = {0, 0, 0, 0, 0, 0, 0, 0};
  if (tid < 128) {
    const float* r = fpart + tid * 8;
    g[0] = cload(r + 0);
    g[1] = cload(r + 1);
    g[2] = cload(r + 2);
    const float* r2 = fpart + (128 + tid) * 8;
    g[3] = cload(r2 + 0);
    g[4] = cload(r2 + 1);
  }
  if (tid < 8) g[5] = cload(fpart + (256 + tid) * 8);
  if (tid < BB) {
    float hit = 0.0f, eh = 0.0f, mk = 0.0f;
#pragma unroll
    for (int k = 0; k < 4; k++) {
      hit += cload(fpart + (4 * tid + k) * 8 + 3);
      eh += cload(fpart + (4 * tid + k) * 8 + 4);
      mk += cload(fpart + (128 + 4 * tid + k) * 8 + 2);
    }
    float dh = hit - mk;
    g[6] = dh * dh;
    float de = eh - e_init[tid];
    g[7] = de * de;
  }
  for (int k = 0; k < 8; k++) {
    float v = g[k];
    v += __shfl_down(v, 32);
    v += __shfl_down(v, 16);
    v += __shfl_down(v, 8);
    v += __shfl_down(v, 4);
    v += __shfl_down(v, 2);
    v += __shfl_down(v, 1);
    if (lane == 0) red[wave][k] = v;
  }
  __syncthreads();
  if (tid == 0) {
    float s[8];
    for (int k = 0; k < 8; k++) s[k] = red[0][k] + red[1][k] + red[2][k] + red[3][k];
    const float invBN = 1.0f / (float)(BB * NP);
    float chamfer_pred = s[0] * invBN;
    float localE = s[1] * invBN;
    float ent = -s[2] * invBN;
    float chamfer_tgt = s[3] / s[4];
    float kld = -0.5f * s[5] / (float)BB;
    float hit = s[6] / (float)BB;
    float ge = s[7] / (float)BB;

    float loss_chamf = (chamfer_tgt + chamfer_pred) * 0.001f;  // LAMBDA_CHAMFER
    float losskld = kl_weight[0] * kld;
    float loss_ge = 10.0f * ge;    // LAMBDA_E_SUM
    float loss_hit = 20.0f * hit;  // LAMBDA_HIT
    float loss_ent = 0.1f * ent;   // LAMBDA_HIT_ENTROPY

    float total = loss_chamf + localE + losskld + loss_ge + loss_hit + loss_ent;
    out[0] = total;
    out[1] = loss_chamf;
    out[2] = localE;
    out[3] = loss_ge;
    out[4] = loss_hit;
    out[5] = losskld;
  }
}

extern "C" void kernel_launch(void* const* d_in, const int* in_sizes, int n_in,
                              void* d_out, int out_size, void* d_ws, size_t ws_size,
                              hipStream_t stream) {
  const float* preds = (const float*)d_in[0];
  const float* target = (const float*)d_in[1];
  const float* mask = (const float*)d_in[2];
  const float* mu = (const float*)d_in[3];
  const float* logvar = (const float*)d_in[4];
  const float* e_init = (const float*)d_in[5];
  const float* kl_weight = (const float*)d_in[6];
  float* fpart = (float*)((char*)d_ws + FPART_OFF);
  unsigned* cnt = (unsigned*)((char*)d_ws + CNT_OFF);
  unsigned long long* ppart = (unsigned long long*)((char*)d_ws + PPART_OFF);
  float* tpart = (float*)((char*)d_ws + TPART_OFF);
  float* out = (float*)d_out;

  k_pair<<<2048, 256, 0, stream>>>(preds, target, mask, ppart, tpart, cnt);
  k_fin<<<264, 256, 0, stream>>>(ppart, tpart, preds, target, mask, mu, logvar,
                                 e_init, kl_weight, fpart, cnt, out);
}